// Round 5
// baseline (1084.797 us; speedup 1.0000x reference)
//
#include <hip/hip_runtime.h>
#include <stdint.h>

#define NSTEPS 40
#define SBS 264   // LDS state-row stride in elements (256 + 8 pad; 528 B, 16B-aligned)

typedef float    floatx4  __attribute__((ext_vector_type(4)));
typedef __bf16   bf16x8   __attribute__((ext_vector_type(8)));
typedef uint32_t uint32x2 __attribute__((ext_vector_type(2)));

__device__ __forceinline__ __bf16 f2bf(float f){
  union { float f; uint32_t u; } v; v.f = f;
  uint32_t r = v.u + 0x7FFFu + ((v.u >> 16) & 1u);   // RNE (prep kernel only)
  union { uint16_t s; __bf16 b; } o; o.s = (uint16_t)(r >> 16);
  return o.b;
}
__device__ __forceinline__ float bf2f(__bf16 b){
  union { uint16_t s; __bf16 b; } i; i.b = b;
  union { uint32_t u; float f; } o; o.u = ((uint32_t)i.s) << 16;
  return o.f;
}
// HW packed f32x2 -> bf16x2 (RNE), 1 instruction
__device__ __forceinline__ uint32_t cvt_pk_bf16(float lo, float hi){
  uint32_t d;
  asm("v_cvt_pk_bf16_f32 %0, %1, %2" : "=v"(d) : "v"(lo), "v"(hi));
  return d;
}
__device__ __forceinline__ float fast_tanh(float x){
  float e = __expf(2.0f * x);
  return __builtin_fmaf(-2.0f, __builtin_amdgcn_rcpf(e + 1.0f), 1.0f);
}

// ---- prep: bf16-cast + transpose weights into workspace (proven) ----
__global__ void prep_kernel(const float* __restrict__ Ws,
                            const float* __restrict__ W1,
                            const float* __restrict__ W2,
                            __bf16* __restrict__ WsT,
                            __bf16* __restrict__ W1T,
                            __bf16* __restrict__ W2T){
  int tid = blockIdx.x * blockDim.x + threadIdx.x;
  int stride = gridDim.x * blockDim.x;
  for (int i = tid; i < 512*256; i += stride){
    int k = i >> 8, n = i & 255;
    WsT[n*512 + k] = f2bf(Ws[i]);
  }
  for (int i = tid; i < 256*256; i += stride){
    int k = i >> 8, n = i & 255;
    W1T[n*256 + k] = f2bf(W1[i]);
    W2T[n*256 + k] = f2bf(W2[i]);
  }
}

// Fused ODE kernel. Block = 32 batch rows, 256 threads (4 waves, 1 wave/SIMD,
// full 512-VGPR budget). Each wave owns 64 hid rows; W1^T/W2^T A-fragments
// live permanently in registers (128+128 VGPRs). State buffers in LDS use a
// PADDED LINEAR layout (row stride SBS=264 elems): addr = batch*SBS + hid.
// No swizzle — trivially correct; b128 reads are 2-way bank-aliased (free).
// 2 barriers per eval (double-buffered SB0=h_eval, SB1=z).
__global__ __launch_bounds__(256, 1)
void ode_kernel(const float* __restrict__ x,
                const float* __restrict__ b_state,
                const float* __restrict__ W1full,   // 257x256 fp32 (row 256 = t row)
                const float* __restrict__ b1,
                const float* __restrict__ b2,
                const float* __restrict__ Wout,     // 256x18 fp32
                const float* __restrict__ bout,
                const __bf16* __restrict__ WsT,     // [256][512]
                const __bf16* __restrict__ W1Tg,    // [256][256]
                const __bf16* __restrict__ W2Tg,    // [256][256]
                float* __restrict__ out)
{
  __shared__ __align__(16) __bf16 lds_sb0[32*SBS];  // 16.5 KB  h_eval
  __shared__ __align__(16) __bf16 lds_sb1[32*SBS];  // 16.5 KB  z
  __shared__ __align__(16) float  lds_bias[3*256];  //  3 KB    b1 | w_t | b2

  const int tid  = threadIdx.x;
  const int wave = tid >> 6;       // 0..3
  const int lane = tid & 63;
  const int c16  = lane & 15;      // MFMA col (batch) / A-row low bits
  const int q    = lane >> 4;      // 0..3 (MFMA quad)
  const int nh0  = wave * 64;      // this wave's hid-row base (64 rows)
  const int m0   = blockIdx.x * 32;

  // ---- stage bias table (read first after barrier A of eval 0) ----
  lds_bias[tid]       = b1[tid];
  lds_bias[256 + tid] = W1full[256*256 + tid];  // time row of W_dyn1
  lds_bias[512 + tid] = b2[tid];

  // ---- per-lane addressing (padded-linear, no swizzle) ----
  // A-operand row (hid) for fragment mt: nh0 + mt*16 + c16
  // B-operand: batch row m = nt*16 + c16, k-offset kt*32 + q*8
  // C/D: hid row n0 = nh0 + mt*16 + 4q + r, batch col = nt*16 + c16
  int arow[4];
  #pragma unroll
  for (int mt = 0; mt < 4; ++mt) arow[mt] = nh0 + mt*16 + c16;
  int brow[2];                      // B batch row * SBS
  #pragma unroll
  for (int nt = 0; nt < 2; ++nt) brow[nt] = (nt*16 + c16) * SBS;
  int woff[4][2];                   // C/D write offsets: batch*SBS + n0
  #pragma unroll
  for (int mt = 0; mt < 4; ++mt){
    int n0 = nh0 + mt*16 + 4*q;
    #pragma unroll
    for (int nt = 0; nt < 2; ++nt)
      woff[mt][nt] = brow[nt] + n0;
  }
  const int bidx = nh0 + 4*q;       // bias row base (add mt*16)

  // ---- resident weight fragments: W1^T, W2^T (A-operands), 256 VGPRs ----
  bf16x8 w1f[4][8], w2f[4][8];
  #pragma unroll
  for (int mt = 0; mt < 4; ++mt)
    #pragma unroll
    for (int kt = 0; kt < 8; ++kt){
      w1f[mt][kt] = *(const bf16x8*)&W1Tg[arow[mt]*256 + kt*32 + q*8];
      w2f[mt][kt] = *(const bf16x8*)&W2Tg[arow[mt]*256 + kt*32 + q*8];
    }

  floatx4 g[4][2], hv[4][2];       // [hid-tile mt][batch-tile nt]

  // ---- phase 0: h0^T = tanh(Ws^T @ x^T + b_state) ----
  {
    #pragma unroll
    for (int mt = 0; mt < 4; ++mt){
      floatx4 bsv;
      #pragma unroll
      for (int r = 0; r < 4; ++r) bsv[r] = b_state[nh0 + mt*16 + 4*q + r];
      #pragma unroll
      for (int nt = 0; nt < 2; ++nt) g[mt][nt] = bsv;
    }
    #pragma unroll 2
    for (int kt = 0; kt < 16; ++kt){
      bf16x8 b[2];
      #pragma unroll
      for (int nt = 0; nt < 2; ++nt){
        const float* px = &x[(size_t)(m0 + nt*16 + c16)*512 + kt*32 + q*8];
        floatx4 f0 = *(const floatx4*)px;
        floatx4 f1 = *(const floatx4*)(px + 4);
        union { uint32_t u[4]; bf16x8 v; } pk;
        pk.u[0] = cvt_pk_bf16(f0[0], f0[1]);
        pk.u[1] = cvt_pk_bf16(f0[2], f0[3]);
        pk.u[2] = cvt_pk_bf16(f1[0], f1[1]);
        pk.u[3] = cvt_pk_bf16(f1[2], f1[3]);
        b[nt] = pk.v;
      }
      #pragma unroll
      for (int mt = 0; mt < 4; ++mt){
        bf16x8 a = *(const bf16x8*)&WsT[arow[mt]*512 + kt*32 + q*8];
        #pragma unroll
        for (int nt = 0; nt < 2; ++nt)
          g[mt][nt] = __builtin_amdgcn_mfma_f32_16x16x32_bf16(a, b[nt], g[mt][nt], 0, 0, 0);
      }
    }
    #pragma unroll
    for (int mt = 0; mt < 4; ++mt)
      #pragma unroll
      for (int nt = 0; nt < 2; ++nt)
        #pragma unroll
        for (int r = 0; r < 4; ++r)
          hv[mt][nt][r] = fast_tanh(g[mt][nt][r]);
  }

  const float dt  = 1.0f / NSTEPS;
  const float dt6 = dt / 6.0f;
  const floatx4 vzero = {0.f, 0.f, 0.f, 0.f};

  #pragma unroll 1
  for (int s = 0; s < NSTEPS; ++s){
    float tbase = dt * (float)s;
    floatx4 sm[4][2];
    #pragma unroll
    for (int mt = 0; mt < 4; ++mt)
      #pragma unroll
      for (int nt = 0; nt < 2; ++nt)
        sm[mt][nt] = vzero;

    #pragma unroll 1
    for (int e = 0; e < 4; ++e){
      float half_or_full = (e == 3) ? dt : 0.5f * dt;
      float cin = (e == 0) ? 0.0f : half_or_full;   // h_eval = h + cin*k_prev
      float te  = tbase + ((e == 0) ? 0.0f : half_or_full);
      float we  = (e == 1 || e == 2) ? 2.0f : 1.0f;

      // write h_eval -> SB0 (g = k_{e-1}; cin=0 at e=0).
      // SB0's last readers (GEMM1 of prev eval) passed barrier B since.
      #pragma unroll
      for (int mt = 0; mt < 4; ++mt)
        #pragma unroll
        for (int nt = 0; nt < 2; ++nt){
          float v0 = __builtin_fmaf(cin, g[mt][nt][0], hv[mt][nt][0]);
          float v1 = __builtin_fmaf(cin, g[mt][nt][1], hv[mt][nt][1]);
          float v2 = __builtin_fmaf(cin, g[mt][nt][2], hv[mt][nt][2]);
          float v3 = __builtin_fmaf(cin, g[mt][nt][3], hv[mt][nt][3]);
          uint32x2 wv = { cvt_pk_bf16(v0, v1), cvt_pk_bf16(v2, v3) };
          *(uint32x2*)&lds_sb0[woff[mt][nt]] = wv;   // 8B at batch*SBS + n0 (n0%4==0)
        }
      __syncthreads();   // barrier A

      // GEMM1: z^T = W1^T @ h_eval^T (+ b1 + t*w_t); A resident in regs
      #pragma unroll
      for (int mt = 0; mt < 4; ++mt){
        floatx4 b1v = *(const floatx4*)&lds_bias[bidx + mt*16];
        floatx4 wtv = *(const floatx4*)&lds_bias[256 + bidx + mt*16];
        floatx4 bias;
        #pragma unroll
        for (int r = 0; r < 4; ++r) bias[r] = __builtin_fmaf(te, wtv[r], b1v[r]);
        #pragma unroll
        for (int nt = 0; nt < 2; ++nt) g[mt][nt] = bias;
      }
      #pragma unroll
      for (int kt = 0; kt < 8; ++kt){
        bf16x8 b[2];
        #pragma unroll
        for (int nt = 0; nt < 2; ++nt)
          b[nt] = *(const bf16x8*)&lds_sb0[brow[nt] + kt*32 + q*8];
        #pragma unroll
        for (int mt = 0; mt < 4; ++mt)
          #pragma unroll
          for (int nt = 0; nt < 2; ++nt)
            g[mt][nt] = __builtin_amdgcn_mfma_f32_16x16x32_bf16(w1f[mt][kt], b[nt], g[mt][nt], 0, 0, 0);
      }

      // z = tanh(.) -> SB1. SB1's last readers (GEMM2 of prev eval) passed
      // barrier A since.
      #pragma unroll
      for (int mt = 0; mt < 4; ++mt)
        #pragma unroll
        for (int nt = 0; nt < 2; ++nt){
          float v0 = fast_tanh(g[mt][nt][0]);
          float v1 = fast_tanh(g[mt][nt][1]);
          float v2 = fast_tanh(g[mt][nt][2]);
          float v3 = fast_tanh(g[mt][nt][3]);
          uint32x2 wv = { cvt_pk_bf16(v0, v1), cvt_pk_bf16(v2, v3) };
          *(uint32x2*)&lds_sb1[woff[mt][nt]] = wv;
        }
      __syncthreads();   // barrier B

      // GEMM2: k^T = W2^T @ z^T (+b2); A resident in regs
      #pragma unroll
      for (int mt = 0; mt < 4; ++mt){
        floatx4 b2v = *(const floatx4*)&lds_bias[512 + bidx + mt*16];
        #pragma unroll
        for (int nt = 0; nt < 2; ++nt) g[mt][nt] = b2v;
      }
      #pragma unroll
      for (int kt = 0; kt < 8; ++kt){
        bf16x8 b[2];
        #pragma unroll
        for (int nt = 0; nt < 2; ++nt)
          b[nt] = *(const bf16x8*)&lds_sb1[brow[nt] + kt*32 + q*8];
        #pragma unroll
        for (int mt = 0; mt < 4; ++mt)
          #pragma unroll
          for (int nt = 0; nt < 2; ++nt)
            g[mt][nt] = __builtin_amdgcn_mfma_f32_16x16x32_bf16(w2f[mt][kt], b[nt], g[mt][nt], 0, 0, 0);
      }

      // RK4 sum
      #pragma unroll
      for (int mt = 0; mt < 4; ++mt)
        #pragma unroll
        for (int nt = 0; nt < 2; ++nt)
          #pragma unroll
          for (int r = 0; r < 4; ++r)
            sm[mt][nt][r] = __builtin_fmaf(we, g[mt][nt][r], sm[mt][nt][r]);
    } // evals

    #pragma unroll
    for (int mt = 0; mt < 4; ++mt)
      #pragma unroll
      for (int nt = 0; nt < 2; ++nt)
        #pragma unroll
        for (int r = 0; r < 4; ++r)
          hv[mt][nt][r] = __builtin_fmaf(dt6, sm[mt][nt][r], hv[mt][nt][r]);
  } // steps

  // ---- epilogue: h_T -> SB0, then out = h_T @ Wout + bout ----
  // SB0 safe (last readers passed barrier B of final eval).
  #pragma unroll
  for (int mt = 0; mt < 4; ++mt)
    #pragma unroll
    for (int nt = 0; nt < 2; ++nt){
      uint32x2 wv = { cvt_pk_bf16(hv[mt][nt][0], hv[mt][nt][1]),
                      cvt_pk_bf16(hv[mt][nt][2], hv[mt][nt][3]) };
      *(uint32x2*)&lds_sb0[woff[mt][nt]] = wv;
    }
  __syncthreads();
  {
    const int r  = tid & 31;         // batch row within block
    const int og = tid >> 5;         // 8 groups; first 6 cover 18 outputs
    if (og < 6){
      const int obase = og * 3;
      float acc[3] = {0.f, 0.f, 0.f};
      for (int c = 0; c < 32; ++c){
        bf16x8 h8 = *(const bf16x8*)&lds_sb0[r*SBS + c*8];
        #pragma unroll
        for (int j = 0; j < 8; ++j){
          float hval = bf2f(h8[j]);
          int kk = c*8 + j;
          #pragma unroll
          for (int oo = 0; oo < 3; ++oo)
            acc[oo] += hval * Wout[kk*18 + obase + oo];
        }
      }
      #pragma unroll
      for (int oo = 0; oo < 3; ++oo)
        out[(size_t)(m0 + r)*18 + obase + oo] = acc[oo] + bout[obase + oo];
    }
  }
}

extern "C" void kernel_launch(void* const* d_in, const int* in_sizes, int n_in,
                              void* d_out, int out_size, void* d_ws, size_t ws_size,
                              hipStream_t stream){
  const float* x   = (const float*)d_in[0];
  const float* Ws  = (const float*)d_in[1];
  const float* bs  = (const float*)d_in[2];
  const float* W1  = (const float*)d_in[3];
  const float* b1  = (const float*)d_in[4];
  const float* W2  = (const float*)d_in[5];
  const float* b2  = (const float*)d_in[6];
  const float* Wo  = (const float*)d_in[7];
  const float* bo  = (const float*)d_in[8];
  float* out = (float*)d_out;

  __bf16* WsT = (__bf16*)d_ws;          // 256x512 bf16 = 256 KB
  __bf16* W1T = WsT + 512*256;          // 256x256 bf16 = 128 KB
  __bf16* W2T = W1T + 256*256;          // 256x256 bf16 = 128 KB

  prep_kernel<<<128, 256, 0, stream>>>(Ws, W1, W2, WsT, W1T, W2T);
  ode_kernel<<<512, 256, 0, stream>>>(x, bs, W1, b1, b2, Wo, bo, WsT, W1T, W2T, out);
}

// Round 6
// 1081.108 us; speedup vs baseline: 1.0034x; 1.0034x over previous
//
#include <hip/hip_runtime.h>
#include <stdint.h>

#define NSTEPS 40
#define SBS 264   // LDS state-row stride in elements (256 + 8 pad; 528 B, 16B-aligned)

typedef float    floatx4  __attribute__((ext_vector_type(4)));
typedef __bf16   bf16x8   __attribute__((ext_vector_type(8)));
typedef uint32_t uint32x2 __attribute__((ext_vector_type(2)));

__device__ __forceinline__ __bf16 f2bf(float f){
  union { float f; uint32_t u; } v; v.f = f;
  uint32_t r = v.u + 0x7FFFu + ((v.u >> 16) & 1u);   // RNE (prep kernel only)
  union { uint16_t s; __bf16 b; } o; o.s = (uint16_t)(r >> 16);
  return o.b;
}
__device__ __forceinline__ float bf2f(__bf16 b){
  union { uint16_t s; __bf16 b; } i; i.b = b;
  union { uint32_t u; float f; } o; o.u = ((uint32_t)i.s) << 16;
  return o.f;
}
// HW packed f32x2 -> bf16x2 (RNE), 1 instruction
__device__ __forceinline__ uint32_t cvt_pk_bf16(float lo, float hi){
  uint32_t d;
  asm("v_cvt_pk_bf16_f32 %0, %1, %2" : "=v"(d) : "v"(lo), "v"(hi));
  return d;
}
__device__ __forceinline__ float fast_tanh(float x){
  float e = __expf(2.0f * x);
  return __builtin_fmaf(-2.0f, __builtin_amdgcn_rcpf(e + 1.0f), 1.0f);
}

// ---- prep: bf16-cast + transpose weights into workspace (proven) ----
__global__ void prep_kernel(const float* __restrict__ Ws,
                            const float* __restrict__ W1,
                            const float* __restrict__ W2,
                            __bf16* __restrict__ WsT,
                            __bf16* __restrict__ W1T,
                            __bf16* __restrict__ W2T){
  int tid = blockIdx.x * blockDim.x + threadIdx.x;
  int stride = gridDim.x * blockDim.x;
  for (int i = tid; i < 512*256; i += stride){
    int k = i >> 8, n = i & 255;
    WsT[n*512 + k] = f2bf(Ws[i]);
  }
  for (int i = tid; i < 256*256; i += stride){
    int k = i >> 8, n = i & 255;
    W1T[n*256 + k] = f2bf(W1[i]);
    W2T[n*256 + k] = f2bf(W2[i]);
  }
}

// Fused ODE kernel. Block = 32 batch rows, 256 threads (4 waves, 1 wave/SIMD,
// full 512-VGPR budget). Each wave owns 64 hid rows; W1^T/W2^T A-fragments
// live permanently in registers (128+128 VGPRs), PINNED via empty asm so the
// compiler cannot rematerialize them as per-eval global reloads (round 5
// failure mode: VGPR_Count=236 + ~256KB/eval-CU L2 weight traffic -> L2-bound).
// State buffers in LDS, padded linear layout (row stride SBS=264):
// addr = batch*SBS + hid. 2 barriers per eval (SB0=h_eval, SB1=z).
__global__ __launch_bounds__(256, 1)
void ode_kernel(const float* __restrict__ x,
                const float* __restrict__ b_state,
                const float* __restrict__ W1full,   // 257x256 fp32 (row 256 = t row)
                const float* __restrict__ b1,
                const float* __restrict__ b2,
                const float* __restrict__ Wout,     // 256x18 fp32
                const float* __restrict__ bout,
                const __bf16* __restrict__ WsT,     // [256][512]
                const __bf16* __restrict__ W1Tg,    // [256][256]
                const __bf16* __restrict__ W2Tg,    // [256][256]
                float* __restrict__ out)
{
  __shared__ __align__(16) __bf16 lds_sb0[32*SBS];  // 16.5 KB  h_eval
  __shared__ __align__(16) __bf16 lds_sb1[32*SBS];  // 16.5 KB  z
  __shared__ __align__(16) float  lds_bias[3*256];  //  3 KB    b1 | w_t | b2

  const int tid  = threadIdx.x;
  const int wave = tid >> 6;       // 0..3
  const int lane = tid & 63;
  const int c16  = lane & 15;      // MFMA col (batch) / A-row low bits
  const int q    = lane >> 4;      // 0..3 (MFMA quad)
  const int nh0  = wave * 64;      // this wave's hid-row base (64 rows)
  const int m0   = blockIdx.x * 32;

  // ---- stage bias table (read first after barrier A of eval 0) ----
  lds_bias[tid]       = b1[tid];
  lds_bias[256 + tid] = W1full[256*256 + tid];  // time row of W_dyn1
  lds_bias[512 + tid] = b2[tid];

  // ---- per-lane addressing (padded-linear, no swizzle) ----
  int arow[4];
  #pragma unroll
  for (int mt = 0; mt < 4; ++mt) arow[mt] = nh0 + mt*16 + c16;
  int brow[2];                      // B batch row * SBS
  #pragma unroll
  for (int nt = 0; nt < 2; ++nt) brow[nt] = (nt*16 + c16) * SBS;
  int woff[4][2];                   // C/D write offsets: batch*SBS + n0
  #pragma unroll
  for (int mt = 0; mt < 4; ++mt){
    int n0 = nh0 + mt*16 + 4*q;
    #pragma unroll
    for (int nt = 0; nt < 2; ++nt)
      woff[mt][nt] = brow[nt] + n0;
  }
  const int bidx = nh0 + 4*q;       // bias row base (add mt*16)

  // ---- resident weight fragments: W1^T, W2^T (A-operands), 256 VGPRs ----
  bf16x8 w1f[4][8], w2f[4][8];
  #pragma unroll
  for (int mt = 0; mt < 4; ++mt)
    #pragma unroll
    for (int kt = 0; kt < 8; ++kt){
      w1f[mt][kt] = *(const bf16x8*)&W1Tg[arow[mt]*256 + kt*32 + q*8];
      w2f[mt][kt] = *(const bf16x8*)&W2Tg[arow[mt]*256 + kt*32 + q*8];
    }
  // PIN: make fragments opaque so they cannot be rematerialized from memory.
  #pragma unroll
  for (int mt = 0; mt < 4; ++mt)
    #pragma unroll
    for (int kt = 0; kt < 8; ++kt)
      asm volatile("" : "+v"(w1f[mt][kt]), "+v"(w2f[mt][kt]));

  floatx4 g[4][2], hv[4][2];       // [hid-tile mt][batch-tile nt]

  // ---- phase 0: h0^T = tanh(Ws^T @ x^T + b_state) ----
  {
    #pragma unroll
    for (int mt = 0; mt < 4; ++mt){
      floatx4 bsv;
      #pragma unroll
      for (int r = 0; r < 4; ++r) bsv[r] = b_state[nh0 + mt*16 + 4*q + r];
      #pragma unroll
      for (int nt = 0; nt < 2; ++nt) g[mt][nt] = bsv;
    }
    #pragma unroll 2
    for (int kt = 0; kt < 16; ++kt){
      bf16x8 b[2];
      #pragma unroll
      for (int nt = 0; nt < 2; ++nt){
        const float* px = &x[(size_t)(m0 + nt*16 + c16)*512 + kt*32 + q*8];
        floatx4 f0 = *(const floatx4*)px;
        floatx4 f1 = *(const floatx4*)(px + 4);
        union { uint32_t u[4]; bf16x8 v; } pk;
        pk.u[0] = cvt_pk_bf16(f0[0], f0[1]);
        pk.u[1] = cvt_pk_bf16(f0[2], f0[3]);
        pk.u[2] = cvt_pk_bf16(f1[0], f1[1]);
        pk.u[3] = cvt_pk_bf16(f1[2], f1[3]);
        b[nt] = pk.v;
      }
      #pragma unroll
      for (int mt = 0; mt < 4; ++mt){
        bf16x8 a = *(const bf16x8*)&WsT[arow[mt]*512 + kt*32 + q*8];
        #pragma unroll
        for (int nt = 0; nt < 2; ++nt)
          g[mt][nt] = __builtin_amdgcn_mfma_f32_16x16x32_bf16(a, b[nt], g[mt][nt], 0, 0, 0);
      }
    }
    #pragma unroll
    for (int mt = 0; mt < 4; ++mt)
      #pragma unroll
      for (int nt = 0; nt < 2; ++nt)
        #pragma unroll
        for (int r = 0; r < 4; ++r)
          hv[mt][nt][r] = fast_tanh(g[mt][nt][r]);
  }

  const float dt  = 1.0f / NSTEPS;
  const float dt6 = dt / 6.0f;
  const floatx4 vzero = {0.f, 0.f, 0.f, 0.f};

  #pragma unroll 1
  for (int s = 0; s < NSTEPS; ++s){
    float tbase = dt * (float)s;
    floatx4 sm[4][2];
    #pragma unroll
    for (int mt = 0; mt < 4; ++mt)
      #pragma unroll
      for (int nt = 0; nt < 2; ++nt)
        sm[mt][nt] = vzero;

    #pragma unroll 1
    for (int e = 0; e < 4; ++e){
      float half_or_full = (e == 3) ? dt : 0.5f * dt;
      float cin = (e == 0) ? 0.0f : half_or_full;   // h_eval = h + cin*k_prev
      float te  = tbase + ((e == 0) ? 0.0f : half_or_full);
      float we  = (e == 1 || e == 2) ? 2.0f : 1.0f;

      // write h_eval -> SB0 (g = k_{e-1}; cin=0 at e=0).
      // SB0's last readers (GEMM1 of prev eval) passed barrier B since.
      #pragma unroll
      for (int mt = 0; mt < 4; ++mt)
        #pragma unroll
        for (int nt = 0; nt < 2; ++nt){
          float v0 = __builtin_fmaf(cin, g[mt][nt][0], hv[mt][nt][0]);
          float v1 = __builtin_fmaf(cin, g[mt][nt][1], hv[mt][nt][1]);
          float v2 = __builtin_fmaf(cin, g[mt][nt][2], hv[mt][nt][2]);
          float v3 = __builtin_fmaf(cin, g[mt][nt][3], hv[mt][nt][3]);
          uint32x2 wv = { cvt_pk_bf16(v0, v1), cvt_pk_bf16(v2, v3) };
          *(uint32x2*)&lds_sb0[woff[mt][nt]] = wv;   // 8B at batch*SBS + n0
        }
      __syncthreads();   // barrier A

      // GEMM1: z^T = W1^T @ h_eval^T (+ b1 + t*w_t); A resident in regs
      #pragma unroll
      for (int mt = 0; mt < 4; ++mt){
        floatx4 b1v = *(const floatx4*)&lds_bias[bidx + mt*16];
        floatx4 wtv = *(const floatx4*)&lds_bias[256 + bidx + mt*16];
        floatx4 bias;
        #pragma unroll
        for (int r = 0; r < 4; ++r) bias[r] = __builtin_fmaf(te, wtv[r], b1v[r]);
        #pragma unroll
        for (int nt = 0; nt < 2; ++nt) g[mt][nt] = bias;
      }
      #pragma unroll
      for (int kt = 0; kt < 8; ++kt){
        bf16x8 b[2];
        #pragma unroll
        for (int nt = 0; nt < 2; ++nt)
          b[nt] = *(const bf16x8*)&lds_sb0[brow[nt] + kt*32 + q*8];
        #pragma unroll
        for (int mt = 0; mt < 4; ++mt)
          #pragma unroll
          for (int nt = 0; nt < 2; ++nt)
            g[mt][nt] = __builtin_amdgcn_mfma_f32_16x16x32_bf16(w1f[mt][kt], b[nt], g[mt][nt], 0, 0, 0);
      }

      // z = tanh(.) -> SB1. SB1's last readers (GEMM2 of prev eval) passed
      // barrier A since.
      #pragma unroll
      for (int mt = 0; mt < 4; ++mt)
        #pragma unroll
        for (int nt = 0; nt < 2; ++nt){
          float v0 = fast_tanh(g[mt][nt][0]);
          float v1 = fast_tanh(g[mt][nt][1]);
          float v2 = fast_tanh(g[mt][nt][2]);
          float v3 = fast_tanh(g[mt][nt][3]);
          uint32x2 wv = { cvt_pk_bf16(v0, v1), cvt_pk_bf16(v2, v3) };
          *(uint32x2*)&lds_sb1[woff[mt][nt]] = wv;
        }
      __syncthreads();   // barrier B

      // GEMM2: k^T = W2^T @ z^T (+b2); A resident in regs
      #pragma unroll
      for (int mt = 0; mt < 4; ++mt){
        floatx4 b2v = *(const floatx4*)&lds_bias[512 + bidx + mt*16];
        #pragma unroll
        for (int nt = 0; nt < 2; ++nt) g[mt][nt] = b2v;
      }
      #pragma unroll
      for (int kt = 0; kt < 8; ++kt){
        bf16x8 b[2];
        #pragma unroll
        for (int nt = 0; nt < 2; ++nt)
          b[nt] = *(const bf16x8*)&lds_sb1[brow[nt] + kt*32 + q*8];
        #pragma unroll
        for (int mt = 0; mt < 4; ++mt)
          #pragma unroll
          for (int nt = 0; nt < 2; ++nt)
            g[mt][nt] = __builtin_amdgcn_mfma_f32_16x16x32_bf16(w2f[mt][kt], b[nt], g[mt][nt], 0, 0, 0);
      }

      // RK4 sum
      #pragma unroll
      for (int mt = 0; mt < 4; ++mt)
        #pragma unroll
        for (int nt = 0; nt < 2; ++nt)
          #pragma unroll
          for (int r = 0; r < 4; ++r)
            sm[mt][nt][r] = __builtin_fmaf(we, g[mt][nt][r], sm[mt][nt][r]);
    } // evals

    #pragma unroll
    for (int mt = 0; mt < 4; ++mt)
      #pragma unroll
      for (int nt = 0; nt < 2; ++nt)
        #pragma unroll
        for (int r = 0; r < 4; ++r)
          hv[mt][nt][r] = __builtin_fmaf(dt6, sm[mt][nt][r], hv[mt][nt][r]);
  } // steps

  // ---- epilogue: h_T -> SB0, then out = h_T @ Wout + bout ----
  #pragma unroll
  for (int mt = 0; mt < 4; ++mt)
    #pragma unroll
    for (int nt = 0; nt < 2; ++nt){
      uint32x2 wv = { cvt_pk_bf16(hv[mt][nt][0], hv[mt][nt][1]),
                      cvt_pk_bf16(hv[mt][nt][2], hv[mt][nt][3]) };
      *(uint32x2*)&lds_sb0[woff[mt][nt]] = wv;
    }
  __syncthreads();
  {
    const int r  = tid & 31;         // batch row within block
    const int og = tid >> 5;         // 8 groups; first 6 cover 18 outputs
    if (og < 6){
      const int obase = og * 3;
      float acc[3] = {0.f, 0.f, 0.f};
      for (int c = 0; c < 32; ++c){
        bf16x8 h8 = *(const bf16x8*)&lds_sb0[r*SBS + c*8];
        #pragma unroll
        for (int j = 0; j < 8; ++j){
          float hval = bf2f(h8[j]);
          int kk = c*8 + j;
          #pragma unroll
          for (int oo = 0; oo < 3; ++oo)
            acc[oo] += hval * Wout[kk*18 + obase + oo];
        }
      }
      #pragma unroll
      for (int oo = 0; oo < 3; ++oo)
        out[(size_t)(m0 + r)*18 + obase + oo] = acc[oo] + bout[obase + oo];
    }
  }
}

extern "C" void kernel_launch(void* const* d_in, const int* in_sizes, int n_in,
                              void* d_out, int out_size, void* d_ws, size_t ws_size,
                              hipStream_t stream){
  const float* x   = (const float*)d_in[0];
  const float* Ws  = (const float*)d_in[1];
  const float* bs  = (const float*)d_in[2];
  const float* W1  = (const float*)d_in[3];
  const float* b1  = (const float*)d_in[4];
  const float* W2  = (const float*)d_in[5];
  const float* b2  = (const float*)d_in[6];
  const float* Wo  = (const float*)d_in[7];
  const float* bo  = (const float*)d_in[8];
  float* out = (float*)d_out;

  __bf16* WsT = (__bf16*)d_ws;          // 256x512 bf16 = 256 KB
  __bf16* W1T = WsT + 512*256;          // 256x256 bf16 = 128 KB
  __bf16* W2T = W1T + 256*256;          // 256x256 bf16 = 128 KB

  prep_kernel<<<128, 256, 0, stream>>>(Ws, W1, W2, WsT, W1T, W2T);
  ode_kernel<<<512, 256, 0, stream>>>(x, bs, W1, b1, b2, Wo, bo, WsT, W1T, W2T, out);
}

// Round 7
// 732.362 us; speedup vs baseline: 1.4812x; 1.4762x over previous
//
#include <hip/hip_runtime.h>
#include <stdint.h>

#define NSTEPS 40
#define SBS 264   // LDS state-row stride in elements (256 + 8 pad; 528 B, 16B-aligned)

typedef float    floatx4  __attribute__((ext_vector_type(4)));
typedef __bf16   bf16x8   __attribute__((ext_vector_type(8)));
typedef uint32_t uint32x2 __attribute__((ext_vector_type(2)));

__device__ __forceinline__ __bf16 f2bf(float f){
  union { float f; uint32_t u; } v; v.f = f;
  uint32_t r = v.u + 0x7FFFu + ((v.u >> 16) & 1u);   // RNE (prep kernel only)
  union { uint16_t s; __bf16 b; } o; o.s = (uint16_t)(r >> 16);
  return o.b;
}
__device__ __forceinline__ float bf2f(__bf16 b){
  union { uint16_t s; __bf16 b; } i; i.b = b;
  union { uint32_t u; float f; } o; o.u = ((uint32_t)i.s) << 16;
  return o.f;
}
// HW packed f32x2 -> bf16x2 (RNE), 1 instruction
__device__ __forceinline__ uint32_t cvt_pk_bf16(float lo, float hi){
  uint32_t d;
  asm("v_cvt_pk_bf16_f32 %0, %1, %2" : "=v"(d) : "v"(lo), "v"(hi));
  return d;
}
__device__ __forceinline__ float fast_tanh(float x){
  float e = __expf(2.0f * x);
  return __builtin_fmaf(-2.0f, __builtin_amdgcn_rcpf(e + 1.0f), 1.0f);
}

// ---- prep: bf16-cast + transpose weights into workspace (proven) ----
__global__ void prep_kernel(const float* __restrict__ Ws,
                            const float* __restrict__ W1,
                            const float* __restrict__ W2,
                            __bf16* __restrict__ WsT,
                            __bf16* __restrict__ W1T,
                            __bf16* __restrict__ W2T){
  int tid = blockIdx.x * blockDim.x + threadIdx.x;
  int stride = gridDim.x * blockDim.x;
  for (int i = tid; i < 512*256; i += stride){
    int k = i >> 8, n = i & 255;
    WsT[n*512 + k] = f2bf(Ws[i]);
  }
  for (int i = tid; i < 256*256; i += stride){
    int k = i >> 8, n = i & 255;
    W1T[n*256 + k] = f2bf(W1[i]);
    W2T[n*256 + k] = f2bf(W2[i]);
  }
}

// Fused ODE kernel. Block = 32 batch rows, 512 threads = 8 waves, 2 waves/SIMD
// (the key change vs rounds 5/6: 1 wave/SIMD serialized VALU+LDS-latency+MFMA
// in one wave -- MfmaUtil 27 + VALUBusy 36, 8400 cyc/eval vs 2483 MFMA floor.
// Two waves per SIMD let tanh/pack/barrier of one wave hide behind MFMA of
// the other, per m114 cross-wave co-scheduling).
// Each wave owns 32 hid rows (mt=0..1): weight fragments = 128 regs/wave,
// accum = 48 -> ~220 regs, fits the 256-reg cap at 2 waves/SIMD without
// spilling (round 3's nt=4 variant needed ~270 and spilled).
// State buffers in LDS, padded linear layout: addr = batch*SBS + hid.
// 2 barriers per eval (SB0=h_eval, SB1=z).
__global__ __launch_bounds__(512, 2)
void ode_kernel(const float* __restrict__ x,
                const float* __restrict__ b_state,
                const float* __restrict__ W1full,   // 257x256 fp32 (row 256 = t row)
                const float* __restrict__ b1,
                const float* __restrict__ b2,
                const float* __restrict__ Wout,     // 256x18 fp32
                const float* __restrict__ bout,
                const __bf16* __restrict__ WsT,     // [256][512]
                const __bf16* __restrict__ W1Tg,    // [256][256]
                const __bf16* __restrict__ W2Tg,    // [256][256]
                float* __restrict__ out)
{
  __shared__ __align__(16) __bf16 lds_sb0[32*SBS];  // 16.5 KB  h_eval
  __shared__ __align__(16) __bf16 lds_sb1[32*SBS];  // 16.5 KB  z
  __shared__ __align__(16) float  lds_bias[3*256];  //  3 KB    b1 | w_t | b2

  const int tid  = threadIdx.x;
  const int wave = tid >> 6;       // 0..7
  const int lane = tid & 63;
  const int c16  = lane & 15;      // MFMA col (batch) / A-row low bits
  const int q    = lane >> 4;      // 0..3 (MFMA quad)
  const int nh0  = wave * 32;      // this wave's hid-row base (32 rows)
  const int m0   = blockIdx.x * 32;

  // ---- stage bias table (read first after barrier A of eval 0) ----
  if (tid < 256){
    lds_bias[tid]       = b1[tid];
    lds_bias[256 + tid] = W1full[256*256 + tid];  // time row of W_dyn1
    lds_bias[512 + tid] = b2[tid];
  }

  // ---- per-lane addressing (padded-linear, no swizzle) ----
  int arow[2];
  #pragma unroll
  for (int mt = 0; mt < 2; ++mt) arow[mt] = nh0 + mt*16 + c16;
  int brow[2];                      // B batch row * SBS
  #pragma unroll
  for (int nt = 0; nt < 2; ++nt) brow[nt] = (nt*16 + c16) * SBS;
  int woff[2][2];                   // C/D write offsets: batch*SBS + n0
  #pragma unroll
  for (int mt = 0; mt < 2; ++mt){
    int n0 = nh0 + mt*16 + 4*q;
    #pragma unroll
    for (int nt = 0; nt < 2; ++nt)
      woff[mt][nt] = brow[nt] + n0;
  }
  const int bidx = nh0 + 4*q;       // bias row base (add mt*16)

  // ---- resident weight fragments: W1^T, W2^T (A-operands), 128 VGPRs ----
  bf16x8 w1f[2][8], w2f[2][8];
  #pragma unroll
  for (int mt = 0; mt < 2; ++mt)
    #pragma unroll
    for (int kt = 0; kt < 8; ++kt){
      w1f[mt][kt] = *(const bf16x8*)&W1Tg[arow[mt]*256 + kt*32 + q*8];
      w2f[mt][kt] = *(const bf16x8*)&W2Tg[arow[mt]*256 + kt*32 + q*8];
    }
  // PIN: keep fragments opaque (prevents remat-to-global under reg pressure).
  #pragma unroll
  for (int mt = 0; mt < 2; ++mt)
    #pragma unroll
    for (int kt = 0; kt < 8; ++kt)
      asm volatile("" : "+v"(w1f[mt][kt]), "+v"(w2f[mt][kt]));

  floatx4 g[2][2], hv[2][2];       // [hid-tile mt][batch-tile nt]

  // ---- phase 0: h0^T = tanh(Ws^T @ x^T + b_state) ----
  {
    #pragma unroll
    for (int mt = 0; mt < 2; ++mt){
      floatx4 bsv;
      #pragma unroll
      for (int r = 0; r < 4; ++r) bsv[r] = b_state[nh0 + mt*16 + 4*q + r];
      #pragma unroll
      for (int nt = 0; nt < 2; ++nt) g[mt][nt] = bsv;
    }
    #pragma unroll 2
    for (int kt = 0; kt < 16; ++kt){
      bf16x8 b[2];
      #pragma unroll
      for (int nt = 0; nt < 2; ++nt){
        const float* px = &x[(size_t)(m0 + nt*16 + c16)*512 + kt*32 + q*8];
        floatx4 f0 = *(const floatx4*)px;
        floatx4 f1 = *(const floatx4*)(px + 4);
        union { uint32_t u[4]; bf16x8 v; } pk;
        pk.u[0] = cvt_pk_bf16(f0[0], f0[1]);
        pk.u[1] = cvt_pk_bf16(f0[2], f0[3]);
        pk.u[2] = cvt_pk_bf16(f1[0], f1[1]);
        pk.u[3] = cvt_pk_bf16(f1[2], f1[3]);
        b[nt] = pk.v;
      }
      #pragma unroll
      for (int mt = 0; mt < 2; ++mt){
        bf16x8 a = *(const bf16x8*)&WsT[arow[mt]*512 + kt*32 + q*8];
        #pragma unroll
        for (int nt = 0; nt < 2; ++nt)
          g[mt][nt] = __builtin_amdgcn_mfma_f32_16x16x32_bf16(a, b[nt], g[mt][nt], 0, 0, 0);
      }
    }
    #pragma unroll
    for (int mt = 0; mt < 2; ++mt)
      #pragma unroll
      for (int nt = 0; nt < 2; ++nt)
        #pragma unroll
        for (int r = 0; r < 4; ++r)
          hv[mt][nt][r] = fast_tanh(g[mt][nt][r]);
  }

  const float dt  = 1.0f / NSTEPS;
  const float dt6 = dt / 6.0f;
  const floatx4 vzero = {0.f, 0.f, 0.f, 0.f};

  #pragma unroll 1
  for (int s = 0; s < NSTEPS; ++s){
    float tbase = dt * (float)s;
    floatx4 sm[2][2];
    #pragma unroll
    for (int mt = 0; mt < 2; ++mt)
      #pragma unroll
      for (int nt = 0; nt < 2; ++nt)
        sm[mt][nt] = vzero;

    #pragma unroll 1
    for (int e = 0; e < 4; ++e){
      float half_or_full = (e == 3) ? dt : 0.5f * dt;
      float cin = (e == 0) ? 0.0f : half_or_full;   // h_eval = h + cin*k_prev
      float te  = tbase + ((e == 0) ? 0.0f : half_or_full);
      float we  = (e == 1 || e == 2) ? 2.0f : 1.0f;

      // write h_eval -> SB0 (g = k_{e-1}; cin=0 at e=0).
      // SB0's last readers (GEMM1 of prev eval) passed barrier B since.
      #pragma unroll
      for (int mt = 0; mt < 2; ++mt)
        #pragma unroll
        for (int nt = 0; nt < 2; ++nt){
          float v0 = __builtin_fmaf(cin, g[mt][nt][0], hv[mt][nt][0]);
          float v1 = __builtin_fmaf(cin, g[mt][nt][1], hv[mt][nt][1]);
          float v2 = __builtin_fmaf(cin, g[mt][nt][2], hv[mt][nt][2]);
          float v3 = __builtin_fmaf(cin, g[mt][nt][3], hv[mt][nt][3]);
          uint32x2 wv = { cvt_pk_bf16(v0, v1), cvt_pk_bf16(v2, v3) };
          *(uint32x2*)&lds_sb0[woff[mt][nt]] = wv;   // 8B at batch*SBS + n0
        }
      __syncthreads();   // barrier A

      // GEMM1: z^T = W1^T @ h_eval^T (+ b1 + t*w_t); A resident in regs
      #pragma unroll
      for (int mt = 0; mt < 2; ++mt){
        floatx4 b1v = *(const floatx4*)&lds_bias[bidx + mt*16];
        floatx4 wtv = *(const floatx4*)&lds_bias[256 + bidx + mt*16];
        floatx4 bias;
        #pragma unroll
        for (int r = 0; r < 4; ++r) bias[r] = __builtin_fmaf(te, wtv[r], b1v[r]);
        #pragma unroll
        for (int nt = 0; nt < 2; ++nt) g[mt][nt] = bias;
      }
      #pragma unroll
      for (int kt = 0; kt < 8; ++kt){
        bf16x8 b[2];
        #pragma unroll
        for (int nt = 0; nt < 2; ++nt)
          b[nt] = *(const bf16x8*)&lds_sb0[brow[nt] + kt*32 + q*8];
        #pragma unroll
        for (int mt = 0; mt < 2; ++mt)
          #pragma unroll
          for (int nt = 0; nt < 2; ++nt)
            g[mt][nt] = __builtin_amdgcn_mfma_f32_16x16x32_bf16(w1f[mt][kt], b[nt], g[mt][nt], 0, 0, 0);
      }

      // z = tanh(.) -> SB1. SB1's last readers (GEMM2 of prev eval) passed
      // barrier A since.
      #pragma unroll
      for (int mt = 0; mt < 2; ++mt)
        #pragma unroll
        for (int nt = 0; nt < 2; ++nt){
          float v0 = fast_tanh(g[mt][nt][0]);
          float v1 = fast_tanh(g[mt][nt][1]);
          float v2 = fast_tanh(g[mt][nt][2]);
          float v3 = fast_tanh(g[mt][nt][3]);
          uint32x2 wv = { cvt_pk_bf16(v0, v1), cvt_pk_bf16(v2, v3) };
          *(uint32x2*)&lds_sb1[woff[mt][nt]] = wv;
        }
      __syncthreads();   // barrier B

      // GEMM2: k^T = W2^T @ z^T (+b2); A resident in regs
      #pragma unroll
      for (int mt = 0; mt < 2; ++mt){
        floatx4 b2v = *(const floatx4*)&lds_bias[512 + bidx + mt*16];
        #pragma unroll
        for (int nt = 0; nt < 2; ++nt) g[mt][nt] = b2v;
      }
      #pragma unroll
      for (int kt = 0; kt < 8; ++kt){
        bf16x8 b[2];
        #pragma unroll
        for (int nt = 0; nt < 2; ++nt)
          b[nt] = *(const bf16x8*)&lds_sb1[brow[nt] + kt*32 + q*8];
        #pragma unroll
        for (int mt = 0; mt < 2; ++mt)
          #pragma unroll
          for (int nt = 0; nt < 2; ++nt)
            g[mt][nt] = __builtin_amdgcn_mfma_f32_16x16x32_bf16(w2f[mt][kt], b[nt], g[mt][nt], 0, 0, 0);
      }

      // RK4 sum
      #pragma unroll
      for (int mt = 0; mt < 2; ++mt)
        #pragma unroll
        for (int nt = 0; nt < 2; ++nt)
          #pragma unroll
          for (int r = 0; r < 4; ++r)
            sm[mt][nt][r] = __builtin_fmaf(we, g[mt][nt][r], sm[mt][nt][r]);
    } // evals

    #pragma unroll
    for (int mt = 0; mt < 2; ++mt)
      #pragma unroll
      for (int nt = 0; nt < 2; ++nt)
        #pragma unroll
        for (int r = 0; r < 4; ++r)
          hv[mt][nt][r] = __builtin_fmaf(dt6, sm[mt][nt][r], hv[mt][nt][r]);
  } // steps

  // ---- epilogue: h_T -> SB0, then out = h_T @ Wout + bout ----
  #pragma unroll
  for (int mt = 0; mt < 2; ++mt)
    #pragma unroll
    for (int nt = 0; nt < 2; ++nt){
      uint32x2 wv = { cvt_pk_bf16(hv[mt][nt][0], hv[mt][nt][1]),
                      cvt_pk_bf16(hv[mt][nt][2], hv[mt][nt][3]) };
      *(uint32x2*)&lds_sb0[woff[mt][nt]] = wv;
    }
  __syncthreads();
  {
    const int r  = tid & 31;         // batch row within block
    const int og = tid >> 5;         // 16 groups; first 6 cover 18 outputs
    if (og < 6){
      const int obase = og * 3;
      float acc[3] = {0.f, 0.f, 0.f};
      for (int c = 0; c < 32; ++c){
        bf16x8 h8 = *(const bf16x8*)&lds_sb0[r*SBS + c*8];
        #pragma unroll
        for (int j = 0; j < 8; ++j){
          float hval = bf2f(h8[j]);
          int kk = c*8 + j;
          #pragma unroll
          for (int oo = 0; oo < 3; ++oo)
            acc[oo] += hval * Wout[kk*18 + obase + oo];
        }
      }
      #pragma unroll
      for (int oo = 0; oo < 3; ++oo)
        out[(size_t)(m0 + r)*18 + obase + oo] = acc[oo] + bout[obase + oo];
    }
  }
}

extern "C" void kernel_launch(void* const* d_in, const int* in_sizes, int n_in,
                              void* d_out, int out_size, void* d_ws, size_t ws_size,
                              hipStream_t stream){
  const float* x   = (const float*)d_in[0];
  const float* Ws  = (const float*)d_in[1];
  const float* bs  = (const float*)d_in[2];
  const float* W1  = (const float*)d_in[3];
  const float* b1  = (const float*)d_in[4];
  const float* W2  = (const float*)d_in[5];
  const float* b2  = (const float*)d_in[6];
  const float* Wo  = (const float*)d_in[7];
  const float* bo  = (const float*)d_in[8];
  float* out = (float*)d_out;

  __bf16* WsT = (__bf16*)d_ws;          // 256x512 bf16 = 256 KB
  __bf16* W1T = WsT + 512*256;          // 256x256 bf16 = 128 KB
  __bf16* W2T = W1T + 256*256;          // 256x256 bf16 = 128 KB

  prep_kernel<<<128, 256, 0, stream>>>(Ws, W1, W2, WsT, W1T, W2T);
  ode_kernel<<<512, 512, 0, stream>>>(x, bs, W1, b1, b2, Wo, bo, WsT, W1T, W2T, out);
}